// Round 1
// baseline (114.355 us; speedup 1.0000x reference)
//
#include <hip/hip_runtime.h>
#include <hip/hip_bf16.h>
#include <stdint.h>

// ---------------------------------------------------------------------------
// MatrixDFTLayer: out[b,k,c] = sum_n x[b,n] * (c==0 ? R : I)[k,n]
// == one GEMM: C[16384 x 2048] = A[16384 x 1024] * Beff^T,
//    Beff[2k+c][n] = (c ? I : R)[k][n]  (row-interleaved, K-contiguous)
// Plan: fp32->bf16 pre-pass into d_ws, then m97-structure bf16 MFMA GEMM.
// ---------------------------------------------------------------------------

typedef __bf16 bf16x8 __attribute__((ext_vector_type(8)));
typedef float f32x4 __attribute__((ext_vector_type(4)));
typedef unsigned short ushort8 __attribute__((ext_vector_type(8)));

#define M_DIM   16384
#define N_OUT   2048
#define K_DIM   1024
#define X_ELEMS 16777216ull   // 16384*1024
#define B_ELEMS 2097152ull    // 2048*1024

__device__ __forceinline__ unsigned short f2bf(float f) {
    union { float f; unsigned u; } v; v.f = f;
    unsigned r = v.u + 0x7fffu + ((v.u >> 16) & 1u);   // RTNE
    return (unsigned short)(r >> 16);
}

// ---- pre-pass: convert x -> bf16, gather-interleave R/I -> Beff (bf16) ----
__global__ __launch_bounds__(256) void convert_kernel(
    const float* __restrict__ x, const float* __restrict__ R,
    const float* __restrict__ Im,
    unsigned short* __restrict__ xa, unsigned short* __restrict__ Beff)
{
    size_t idx = ((size_t)blockIdx.x * 256 + threadIdx.x) * 8;
    const float* src;
    unsigned short* dst;
    if (idx < X_ELEMS) {
        src = x + idx;
        dst = xa + idx;
    } else {
        size_t t = idx - X_ELEMS;          // linear index in Beff
        size_t j = t >> 10, n = t & 1023;  // Beff row j, col n
        src = ((j & 1) ? Im : R) + (j >> 1) * 1024 + n;
        dst = Beff + t;
    }
    float4 f0 = *(const float4*)src;
    float4 f1 = *(const float4*)(src + 4);
    ushort8 o;
    o[0] = f2bf(f0.x); o[1] = f2bf(f0.y); o[2] = f2bf(f0.z); o[3] = f2bf(f0.w);
    o[4] = f2bf(f1.x); o[5] = f2bf(f1.y); o[6] = f2bf(f1.z); o[7] = f2bf(f1.w);
    *(ushort8*)dst = o;
}

// ---- main GEMM: 128x128 tile, BK=32, 4 waves (2x2), double-buffered LDS ----
#define GLOAD_LDS16(g, l) \
    __builtin_amdgcn_global_load_lds( \
        (const __attribute__((address_space(1))) void*)(g), \
        (__attribute__((address_space(3))) void*)(l), 16, 0, 0)

__global__ __launch_bounds__(256) void dft_gemm(
    const unsigned short* __restrict__ A,   // [16384][1024] bf16 bits
    const unsigned short* __restrict__ B,   // [2048][1024]  bf16 bits
    float* __restrict__ C)                  // [16384][2048] fp32
{
    __shared__ __align__(16) unsigned short As[2][128 * 32];
    __shared__ __align__(16) unsigned short Bs[2][128 * 32];

    const int tid  = threadIdx.x;
    const int lane = tid & 63;
    const int w    = tid >> 6;          // wave id 0..3

    // XCD-aware swizzle (grid=2048, divisible by 8 -> simple form valid)
    const int bid = blockIdx.x;
    const int cpx = gridDim.x >> 3;
    const int swz = (bid & 7) * cpx + (bid >> 3);
    const int tn  = swz & 15;           // 16 col tiles (N=2048/128)
    const int tm  = swz >> 4;           // 128 row tiles (M=16384/128)

    const int wr = w >> 1, wc = w & 1;  // 2x2 wave grid, 64x64 per wave

    f32x4 acc[4][4];
#pragma unroll
    for (int i = 0; i < 4; ++i)
#pragma unroll
        for (int j = 0; j < 4; ++j)
            acc[i][j] = (f32x4){0.f, 0.f, 0.f, 0.f};

    // staging geometry: per call, wave w fills rows [w*16, w*16+16) of a
    // 64-row chunk; lane l -> row w*16 + l/4, col (l&3)*8 (16B per lane)
    const int    srow   = w * 16 + (lane >> 2);
    const int    scol   = (lane & 3) * 8;
    const size_t a_base = (size_t)(tm * 128 + srow) * K_DIM + scol;
    const size_t b_base = (size_t)(tn * 128 + srow) * K_DIM + scol;

    auto stage = [&](int buf, int kt) {
        const unsigned short* ag = A + a_base + kt * 32;
        const unsigned short* bg = B + b_base + kt * 32;
        GLOAD_LDS16(ag,             &As[buf][(w * 16) * 32]);
        GLOAD_LDS16(ag + 64 * K_DIM, &As[buf][(64 + w * 16) * 32]);
        GLOAD_LDS16(bg,             &Bs[buf][(w * 16) * 32]);
        GLOAD_LDS16(bg + 64 * K_DIM, &Bs[buf][(64 + w * 16) * 32]);
    };

    const int arow0 = wr * 64 + (lane & 15);
    const int brow0 = wc * 64 + (lane & 15);
    const int kcol  = (lane >> 4) * 8;

    stage(0, 0);
    int cur = 0;
    for (int kt = 0; kt < K_DIM / 32; ++kt) {
        __syncthreads();                       // staging of buf[cur] complete
        if (kt + 1 < K_DIM / 32) stage(cur ^ 1, kt + 1);

        bf16x8 af[4], bf[4];
#pragma unroll
        for (int i = 0; i < 4; ++i)
            af[i] = *(const bf16x8*)&As[cur][(arow0 + i * 16) * 32 + kcol];
#pragma unroll
        for (int j = 0; j < 4; ++j)
            bf[j] = *(const bf16x8*)&Bs[cur][(brow0 + j * 16) * 32 + kcol];
#pragma unroll
        for (int i = 0; i < 4; ++i)
#pragma unroll
            for (int j = 0; j < 4; ++j)
                acc[i][j] = __builtin_amdgcn_mfma_f32_16x16x32_bf16(
                    af[i], bf[j], acc[i][j], 0, 0, 0);
        cur ^= 1;
    }

    // epilogue: C/D layout col = lane&15, row = (lane>>4)*4 + reg  [m89]
    const int crow0 = tm * 128 + wr * 64 + (lane >> 4) * 4;
    const int ccol0 = tn * 128 + wc * 64 + (lane & 15);
#pragma unroll
    for (int i = 0; i < 4; ++i)
#pragma unroll
        for (int j = 0; j < 4; ++j)
#pragma unroll
            for (int r = 0; r < 4; ++r)
                C[(size_t)(crow0 + i * 16 + r) * N_OUT + ccol0 + j * 16] =
                    acc[i][j][r];
}

// ---- fallback (only if d_ws is too small): naive fp32 ----
__global__ void naive_dft(const float* __restrict__ x, const float* __restrict__ R,
                          const float* __restrict__ Im, float* __restrict__ out)
{
    int gid = blockIdx.x * blockDim.x + threadIdx.x;
    int b = gid >> 10, k = gid & 1023;
    const float* xr = x + (size_t)b * 1024;
    const float* rr = R + (size_t)k * 1024;
    const float* ir = Im + (size_t)k * 1024;
    float sr = 0.f, si = 0.f;
    for (int n = 0; n < 1024; ++n) {
        float v = xr[n];
        sr += v * rr[n];
        si += v * ir[n];
    }
    out[(size_t)gid * 2]     = sr;
    out[(size_t)gid * 2 + 1] = si;
}

extern "C" void kernel_launch(void* const* d_in, const int* in_sizes, int n_in,
                              void* d_out, int out_size, void* d_ws, size_t ws_size,
                              hipStream_t stream)
{
    const float* x  = (const float*)d_in[0];
    const float* R  = (const float*)d_in[1];
    const float* Im = (const float*)d_in[2];
    float* out = (float*)d_out;

    const size_t need = (X_ELEMS + B_ELEMS) * sizeof(unsigned short); // 37.75 MB
    if (ws_size >= need) {
        unsigned short* xa   = (unsigned short*)d_ws;
        unsigned short* Beff = xa + X_ELEMS;
        const int conv_blocks = (int)((X_ELEMS + B_ELEMS) / 8 / 256); // 9216
        convert_kernel<<<conv_blocks, 256, 0, stream>>>(x, R, Im, xa, Beff);
        dft_gemm<<<2048, 256, 0, stream>>>(xa, Beff, out);
    } else {
        naive_dft<<<(M_DIM * K_DIM) / 256, 256, 0, stream>>>(x, R, Im, out);
    }
}

// Round 2
// 89.225 us; speedup vs baseline: 1.2816x; 1.2816x over previous
//
#include <hip/hip_runtime.h>
#include <hip/hip_bf16.h>
#include <stdint.h>

// ---------------------------------------------------------------------------
// MatrixDFTLayer: out[b,k,c] = sum_n x[b,n] * (c==0 ? R : I)[k,n]
// == C[16384 x 2048] = A[16384 x 1024] * Beff^T  (Beff row-interleaved R/I)
// R2: 256x256 8-phase template (T2 swizzle + T3/T4 counted vmcnt + T5).
// ---------------------------------------------------------------------------

typedef __bf16 bf16x8 __attribute__((ext_vector_type(8)));
typedef float f32x4 __attribute__((ext_vector_type(4)));
typedef unsigned short ushort8 __attribute__((ext_vector_type(8)));

#define M_DIM   16384
#define N_OUT   2048
#define K_DIM   1024
#define NT      16            // K tiles of BK=64
#define X_ELEMS 16777216ull   // 16384*1024
#define B_ELEMS 2097152ull    // 2048*1024

__device__ __forceinline__ unsigned short f2bf(float f) {
    union { float f; unsigned u; } v; v.f = f;
    unsigned r = v.u + 0x7fffu + ((v.u >> 16) & 1u);   // RTNE
    return (unsigned short)(r >> 16);
}

// ---- pre-pass: convert x -> bf16, gather-interleave R/I -> Beff (bf16) ----
__global__ __launch_bounds__(256) void convert_kernel(
    const float* __restrict__ x, const float* __restrict__ R,
    const float* __restrict__ Im,
    unsigned short* __restrict__ xa, unsigned short* __restrict__ Beff)
{
    size_t idx = ((size_t)blockIdx.x * 256 + threadIdx.x) * 8;
    const float* src;
    unsigned short* dst;
    if (idx < X_ELEMS) {
        src = x + idx;
        dst = xa + idx;
    } else {
        size_t t = idx - X_ELEMS;          // linear index in Beff
        size_t j = t >> 10, n = t & 1023;  // Beff row j, col n
        src = ((j & 1) ? Im : R) + (j >> 1) * 1024 + n;
        dst = Beff + t;
    }
    float4 f0 = *(const float4*)src;
    float4 f1 = *(const float4*)(src + 4);
    ushort8 o;
    o[0] = f2bf(f0.x); o[1] = f2bf(f0.y); o[2] = f2bf(f0.z); o[3] = f2bf(f0.w);
    o[4] = f2bf(f1.x); o[5] = f2bf(f1.y); o[6] = f2bf(f1.z); o[7] = f2bf(f1.w);
    *(ushort8*)dst = o;
}

#define GLOAD_LDS16(g, l) \
    __builtin_amdgcn_global_load_lds( \
        (const __attribute__((address_space(1))) void*)(g), \
        (__attribute__((address_space(3))) void*)(l), 16, 0, 0)

// ---------------------------------------------------------------------------
// 256x256 tile, BK=64, 8 waves (2Mx4N), double-buffered LDS, 8-phase/2-tiles
// schedule with counted vmcnt. XOR-swizzled LDS (both-sides: pre-swizzled
// global source + swizzled ds_read; linear global_load_lds dest).
// ---------------------------------------------------------------------------
__global__ __launch_bounds__(512, 2) void dft_gemm256(
    const unsigned short* __restrict__ A,   // [16384][1024] bf16 bits
    const unsigned short* __restrict__ B,   // [2048][1024]  bf16 bits
    float* __restrict__ C)                  // [16384][2048] fp32
{
    // [buf][op(0=A,1=B)][256*64] bf16 -> 128 KiB total
    __shared__ __align__(16) unsigned short lds[2][2][16384];

    const int tid  = threadIdx.x;
    const int lane = tid & 63;
    const int w    = tid >> 6;          // wave 0..7
    const int wr   = w >> 2;            // 0..1 (M)
    const int wc   = w & 3;             // 0..3 (N)

    // XCD swizzle: nwg=512 divisible by 8
    const int bid = blockIdx.x;
    const int swz = (bid & 7) * 64 + (bid >> 3);
    const int tn  = swz & 7;            // 8 col tiles
    const int tm  = swz >> 3;           // 64 row tiles

    // ---- staging constants (pre-swizzled global source, linear LDS dest) --
    // one glds call: 512 lanes x 16B = 64 rows x 128B. wave w -> rows w*8..+7
    const int r3    = lane >> 3;                                   // row&7
    const int fx_w  = ((r3 & 3) << 4) | (((r3 >> 2) & 1) << 6);    // byte xor
    const int scol  = ((((lane & 7) * 16) ^ fx_w) >> 1);           // elem col
    const int srow  = w * 8 + r3;                                  // row in 64-chunk
    const size_t a_row0 = (size_t)(tm * 256) * K_DIM;
    const size_t b_row0 = (size_t)(tn * 256) * K_DIM;

    auto stage_half = [&](int buf, int op, int half, int kt) {
        const unsigned short* g = (op ? B : A) + (op ? b_row0 : a_row0)
            + (size_t)(half * 128 + srow) * K_DIM + kt * 64 + scol;
        unsigned short* l0 = &lds[buf][op][half * 8192 + w * 512];
        GLOAD_LDS16(g,              l0);
        GLOAD_LDS16(g + 64 * K_DIM, l0 + 4096);
    };

    // ---- fragment-read constants (swizzled ds_read) -----------------------
    // frag row r = base + (lane&15); r&7 == lane&7 (bases are multiples of 16)
    const int fx_r = ((lane & 3) << 4) | (((lane >> 2) & 1) << 6);
    const int e0   = ((((lane >> 4) & 3) * 16) ^ fx_r) >> 1;        // ks0 elem
    const int e1   = ((64 + ((lane >> 4) & 3) * 16) ^ fx_r) >> 1;   // ks1 elem
    const int arow = (wr * 128 + (lane & 15)) * 64;
    const int brow = (wc * 64  + (lane & 15)) * 64;

    f32x4 acc[8][4];
#pragma unroll
    for (int i = 0; i < 8; ++i)
#pragma unroll
        for (int j = 0; j < 4; ++j)
            acc[i][j] = (f32x4){0.f, 0.f, 0.f, 0.f};

    // ---- prologue: tile0 (A0,A1,B0,B1) + B0(1); leave B0(1) in flight -----
    stage_half(0, 0, 0, 0); stage_half(0, 0, 1, 0);
    stage_half(0, 1, 0, 0); stage_half(0, 1, 1, 0);
    stage_half(1, 1, 0, 1);
    asm volatile("s_waitcnt vmcnt(2)" ::: "memory");
    __builtin_amdgcn_s_barrier();

    bf16x8 af[4], bf[4];
    int buf = 0;
    for (int t = 0; t < NT; ++t) {
        const int nbuf = buf ^ 1;

        // ================= phase q0: acc[0-3][*] ks0 =================
#pragma unroll
        for (int i = 0; i < 4; ++i)
            af[i] = *(const bf16x8*)&lds[buf][0][arow + i * 1024 + e0];
#pragma unroll
        for (int j = 0; j < 4; ++j)
            bf[j] = *(const bf16x8*)&lds[buf][1][brow + j * 1024 + e0];
        if (t + 1 < NT) stage_half(nbuf, 1, 1, t + 1);      // B1(t+1)
        __builtin_amdgcn_s_barrier();
        asm volatile("s_waitcnt lgkmcnt(0)" ::: "memory");
        __builtin_amdgcn_sched_barrier(0);
        __builtin_amdgcn_s_setprio(1);
#pragma unroll
        for (int i = 0; i < 4; ++i)
#pragma unroll
            for (int j = 0; j < 4; ++j)
                acc[i][j] = __builtin_amdgcn_mfma_f32_16x16x32_bf16(
                    af[i], bf[j], acc[i][j], 0, 0, 0);
        __builtin_amdgcn_s_setprio(0);
        __builtin_amdgcn_s_barrier();

        // ================= phase q1: acc[4-7][*] ks0 =================
#pragma unroll
        for (int i = 0; i < 4; ++i)
            af[i] = *(const bf16x8*)&lds[buf][0][arow + (i + 4) * 1024 + e0];
        if (t + 1 < NT) stage_half(nbuf, 0, 0, t + 1);      // A0(t+1)
        __builtin_amdgcn_s_barrier();
        asm volatile("s_waitcnt lgkmcnt(0)" ::: "memory");
        __builtin_amdgcn_sched_barrier(0);
        __builtin_amdgcn_s_setprio(1);
#pragma unroll
        for (int i = 0; i < 4; ++i)
#pragma unroll
            for (int j = 0; j < 4; ++j)
                acc[i + 4][j] = __builtin_amdgcn_mfma_f32_16x16x32_bf16(
                    af[i], bf[j], acc[i + 4][j], 0, 0, 0);
        __builtin_amdgcn_s_setprio(0);
        __builtin_amdgcn_s_barrier();

        // ================= phase q2: acc[0-3][*] ks1 =================
#pragma unroll
        for (int i = 0; i < 4; ++i)
            af[i] = *(const bf16x8*)&lds[buf][0][arow + i * 1024 + e1];
#pragma unroll
        for (int j = 0; j < 4; ++j)
            bf[j] = *(const bf16x8*)&lds[buf][1][brow + j * 1024 + e1];
        if (t + 1 < NT) stage_half(nbuf, 0, 1, t + 1);      // A1(t+1)
        __builtin_amdgcn_s_barrier();
        asm volatile("s_waitcnt lgkmcnt(0)" ::: "memory");
        __builtin_amdgcn_sched_barrier(0);
        __builtin_amdgcn_s_setprio(1);
#pragma unroll
        for (int i = 0; i < 4; ++i)
#pragma unroll
            for (int j = 0; j < 4; ++j)
                acc[i][j] = __builtin_amdgcn_mfma_f32_16x16x32_bf16(
                    af[i], bf[j], acc[i][j], 0, 0, 0);
        __builtin_amdgcn_s_setprio(0);
        __builtin_amdgcn_s_barrier();

        // ================= phase q3: acc[4-7][*] ks1 =================
#pragma unroll
        for (int i = 0; i < 4; ++i)
            af[i] = *(const bf16x8*)&lds[buf][0][arow + (i + 4) * 1024 + e1];
        if (t + 2 < NT) stage_half(buf, 1, 0, t + 2);       // B0(t+2)
        // counted wait: tile t+1 fully staged; keep B0(t+2) in flight
        if (t + 2 < NT)      asm volatile("s_waitcnt vmcnt(2)" ::: "memory");
        else if (t + 1 < NT) asm volatile("s_waitcnt vmcnt(0)" ::: "memory");
        __builtin_amdgcn_s_barrier();
        asm volatile("s_waitcnt lgkmcnt(0)" ::: "memory");
        __builtin_amdgcn_sched_barrier(0);
        __builtin_amdgcn_s_setprio(1);
#pragma unroll
        for (int i = 0; i < 4; ++i)
#pragma unroll
            for (int j = 0; j < 4; ++j)
                acc[i + 4][j] = __builtin_amdgcn_mfma_f32_16x16x32_bf16(
                    af[i], bf[j], acc[i + 4][j], 0, 0, 0);
        __builtin_amdgcn_s_setprio(0);
        __builtin_amdgcn_s_barrier();

        buf = nbuf;
    }

    // ---- epilogue: C/D layout col = lane&15, row = (lane>>4)*4 + reg ------
    const int crow0 = tm * 256 + wr * 128 + ((lane >> 4) << 2);
    const int ccol0 = tn * 256 + wc * 64 + (lane & 15);
#pragma unroll
    for (int i = 0; i < 8; ++i)
#pragma unroll
        for (int j = 0; j < 4; ++j) {
            float* cp = C + (size_t)(crow0 + i * 16) * N_OUT + ccol0 + j * 16;
#pragma unroll
            for (int r = 0; r < 4; ++r)
                cp[(size_t)r * N_OUT] = acc[i][j][r];
        }
}

// ---- fallback (only if d_ws is too small): naive fp32 ----
__global__ void naive_dft(const float* __restrict__ x, const float* __restrict__ R,
                          const float* __restrict__ Im, float* __restrict__ out)
{
    int gid = blockIdx.x * blockDim.x + threadIdx.x;
    int b = gid >> 10, k = gid & 1023;
    const float* xr = x + (size_t)b * 1024;
    const float* rr = R + (size_t)k * 1024;
    const float* ir = Im + (size_t)k * 1024;
    float sr = 0.f, si = 0.f;
    for (int n = 0; n < 1024; ++n) {
        float v = xr[n];
        sr += v * rr[n];
        si += v * ir[n];
    }
    out[(size_t)gid * 2]     = sr;
    out[(size_t)gid * 2 + 1] = si;
}

extern "C" void kernel_launch(void* const* d_in, const int* in_sizes, int n_in,
                              void* d_out, int out_size, void* d_ws, size_t ws_size,
                              hipStream_t stream)
{
    const float* x  = (const float*)d_in[0];
    const float* R  = (const float*)d_in[1];
    const float* Im = (const float*)d_in[2];
    float* out = (float*)d_out;

    const size_t need = (X_ELEMS + B_ELEMS) * sizeof(unsigned short); // 37.75 MB
    if (ws_size >= need) {
        unsigned short* xa   = (unsigned short*)d_ws;
        unsigned short* Beff = xa + X_ELEMS;
        const int conv_blocks = (int)((X_ELEMS + B_ELEMS) / 8 / 256); // 9216
        convert_kernel<<<conv_blocks, 256, 0, stream>>>(x, R, Im, xa, Beff);
        dft_gemm256<<<512, 512, 0, stream>>>(xa, Beff, out);
    } else {
        naive_dft<<<(M_DIM * K_DIM) / 256, 256, 0, stream>>>(x, R, Im, out);
    }
}